// Round 4
// baseline (445.840 us; speedup 1.0000x reference)
//
#include <hip/hip_runtime.h>
#include <cstddef>

#define S 64
#define VOL (64*64*64)      // 262144
#define CIN 32

typedef __attribute__((ext_vector_type(8))) short bf16x8;
typedef __attribute__((ext_vector_type(4))) float floatx4;

struct __attribute__((packed, aligned(4))) fpair { float x, y; };

__device__ __forceinline__ unsigned short f2bf(float f) {
    union { float f; unsigned u; } v; v.f = f;
    unsigned r = v.u + 0x7fffu + ((v.u >> 16) & 1u);   // RNE
    return (unsigned short)(r >> 16);
}
__device__ __forceinline__ float bf2f(unsigned short h) {
    union { unsigned u; float f; } v; v.u = ((unsigned)h) << 16;
    return v.f;
}
__device__ __forceinline__ int iclamp(int v, int lo, int hi) {
    return v < lo ? lo : (v > hi ? hi : v);
}

// Async 16B global -> LDS (DMA, no VGPR round-trip). LDS dst is wave-uniform
// base; lane l lands at base + l*16.
__device__ __forceinline__ void gload_lds16(const void* g, void* l) {
    __builtin_amdgcn_global_load_lds(
        (const __attribute__((address_space(1))) void*)g,
        (__attribute__((address_space(3))) void*)l, 16, 0, 0);
}

// Weight prep: src [co][ci][27] fp32 -> dst [tap][co][ci] bf16 (co<64).
__global__ void prep_w_kernel(const float* __restrict__ w_off,
                              const float* __restrict__ w_reg,
                              unsigned short* __restrict__ wt1,
                              unsigned short* __restrict__ wt2) {
    int i = blockIdx.x * 256 + threadIdx.x;   // i = tap*2048 + co*32 + ci
    if (i >= 27 * 64 * 32) return;
    int ci = i & 31;
    int co = (i >> 5) & 63;
    int tap = i >> 11;
    wt1[i] = f2bf(w_off[(co * 32 + ci) * 27 + tap]);
    wt2[i] = f2bf(w_reg[(co * 32 + ci) * 27 + tap]);
}

// x fp32 [b][c][pos] -> xb bf16 [b][pos][32ci] (channels-fastest, packed u32 pairs).
// Reads coalesced per-c (256B/wave), writes one full 64B line per lane.
__global__ __launch_bounds__(256)
void prepack_kernel(const float* __restrict__ x, unsigned* __restrict__ xb) {
    const unsigned id = blockIdx.x * 256 + threadIdx.x;   // b*VOL + pos
    const int b   = id >> 18;                             // VOL = 2^18
    const int pos = id & (VOL - 1);
    const float* sp = x + (size_t)b * 32 * VOL + pos;
    float v[32];
#pragma unroll
    for (int c = 0; c < 32; ++c) v[c] = sp[(size_t)c * VOL];
    unsigned* dp = xb + (size_t)id * 16;
#pragma unroll
    for (int i = 0; i < 4; ++i) {
        uint4 pk;
        pk.x = (unsigned)f2bf(v[i*8+0]) | ((unsigned)f2bf(v[i*8+1]) << 16);
        pk.y = (unsigned)f2bf(v[i*8+2]) | ((unsigned)f2bf(v[i*8+3]) << 16);
        pk.z = (unsigned)f2bf(v[i*8+4]) | ((unsigned)f2bf(v[i*8+5]) << 16);
        pk.w = (unsigned)f2bf(v[i*8+6]) | ((unsigned)f2bf(v[i*8+7]) << 16);
        *(uint4*)(dp + i*4) = pk;
    }
}

// Implicit-GEMM 3x3x3 conv via MFMA 16x16x32 bf16.  v3.
//
// Input layout: bf16 [b][pos][32ci] (channels fastest) -> one LDS row (z,y) is a
// CONTIGUOUS 4KB global row => staging is pure global_load_lds_dwordx4 (async DMA).
// XOR chunk swizzle (logical 16B chunk jj of slot s stored at physical jj^((s>>1)&3))
// is applied by pre-swizzling the per-lane GLOBAL source address; LDS dest linear.
//
// Block: 256 thr = 4 waves. Output tile: 64co x 256pos = (d0..+1) x (h0..+1) x w0..63.
// Wave wv: dd=wv>>1, hh=wv&1. LDS [row 0..15][slot w 0..63][ci 0..31] bf16 = 64KB.
// A-frag: lane holds W[co=base+(lane&15)][ci=(lane>>4)*8+j].
// B-frag: lane holds X[ci=(lane>>4)*8+j][pos=base+(lane&15)].
// C/D: col(=pos)=lane&15, row(=co)=(lane>>4)*4+reg  [measured m89/m91].
//
// WRITE_OFF epilogue: offsets packed u32 in [b][pos][32c] (lo=offw(c), hi=offh(c+32)),
// stored as uint4 (4 c per lane, contiguous).
template <bool WRITE_OFF>
__global__ __launch_bounds__(256, 2)
void conv_mfma_kernel(const unsigned short* __restrict__ src,  // [b][pos][32] bf16
                      const unsigned short* __restrict__ wt,   // [27][64][32] bf16
                      const float* __restrict__ bias,          // used when !WRITE_OFF
                      void* __restrict__ dstv) {
    __shared__ unsigned short lds[16 * 64 * 32];   // 65536 B

    const int d0 = blockIdx.x * 2;
    const int h0 = blockIdx.y * 2;
    const int b  = blockIdx.z;
    const int t  = threadIdx.x;
    const int lane = t & 63;
    const int wv   = t >> 6;

    // ---- async staging: 4 rows per wave, 4 x 1KB issues per row ----
    const int sl = lane >> 2;                      // slot sub-index 0..15
    const int js = (lane & 3) ^ ((lane >> 3) & 3); // inverse-swizzled source chunk
    const char* sbase = (const char*)src + (size_t)b * VOL * 64;
#pragma unroll
    for (int rr2 = 0; rr2 < 4; ++rr2) {
        const int rowi = (wv << 2) + rr2;
        const int z = d0 - 1 + (rowi >> 2);
        const int y = h0 - 1 + (rowi & 3);
        char* ldsrow = (char*)lds + (rowi << 12);
        if (((unsigned)z < 64u) && ((unsigned)y < 64u)) {
            const char* gb = sbase + ((size_t)(z * 4096 + y * 64)) * 64
                           + (sl << 6) + (js << 4);
#pragma unroll
            for (int k = 0; k < 4; ++k)
                gload_lds16(gb + (k << 10), ldsrow + (k << 10));
        } else {
            const uint4 z4 = make_uint4(0, 0, 0, 0);
#pragma unroll
            for (int k = 0; k < 4; ++k)
                *(uint4*)(ldsrow + (k << 10) + (lane << 4)) = z4;
        }
    }
    __syncthreads();   // drains vmcnt (global_load_lds) + lgkmcnt (zero writes)

    // ---- compute ----
    const int r    = lane & 15;
    const int q    = lane >> 4;
    const int dd   = wv >> 1;     // output d = d0 + dd
    const int hh   = wv & 1;      // output h = h0 + hh

    int P[4][3];
#pragma unroll
    for (int nt = 0; nt < 4; ++nt)
#pragma unroll
        for (int kw = 0; kw < 3; ++kw) {
            const int s  = nt * 16 + r + kw - 1;
            const int sc = s & 63;
            P[nt][kw] = (sc << 6) + ((q ^ ((sc >> 1) & 3)) << 4);
        }

    floatx4 acc[4][4];
#pragma unroll
    for (int mt = 0; mt < 4; ++mt)
#pragma unroll
        for (int nt = 0; nt < 4; ++nt)
#pragma unroll
            for (int rg = 0; rg < 4; ++rg) acc[mt][nt][rg] = 0.f;

    const bf16x8 z8 = {0, 0, 0, 0, 0, 0, 0, 0};

#pragma unroll
    for (int tap = 0; tap < 27; ++tap) {
        const int kd = tap / 9;
        const int kh = (tap % 9) / 3;
        const int kw = tap % 3;
        const int rowb = ((((dd + kd) << 2) + hh + kh) << 12);   // row * 4096 B

        bf16x8 afr[4];
#pragma unroll
        for (int mt = 0; mt < 4; ++mt)
            afr[mt] = *(const bf16x8*)&wt[tap * 2048 + (mt * 16 + r) * 32 + q * 8];

        bf16x8 bfr[4];
#pragma unroll
        for (int nt = 0; nt < 4; ++nt)
            bfr[nt] = *(const bf16x8*)((const char*)lds + rowb + P[nt][kw]);

        if (kw == 0) { if (r == 0)  bfr[0] = z8; }
        if (kw == 2) { if (r == 15) bfr[3] = z8; }

#pragma unroll
        for (int mt = 0; mt < 4; ++mt)
#pragma unroll
            for (int nt = 0; nt < 4; ++nt)
                acc[mt][nt] = __builtin_amdgcn_mfma_f32_16x16x32_bf16(
                                  afr[mt], bfr[nt], acc[mt][nt], 0, 0, 0);
    }

    // ---- epilogue ----
    const int dw = (d0 + dd) * 4096 + (h0 + hh) * 64;
    if (WRITE_OFF) {
        unsigned* dst = (unsigned*)dstv + (size_t)b * VOL * 32;
#pragma unroll
        for (int mt = 0; mt < 2; ++mt) {
#pragma unroll
            for (int nt = 0; nt < 4; ++nt) {
                const int pos = dw + nt * 16 + r;
                uint4 pk;
                pk.x = (unsigned)f2bf(acc[mt][nt][0]) | ((unsigned)f2bf(acc[mt+2][nt][0]) << 16);
                pk.y = (unsigned)f2bf(acc[mt][nt][1]) | ((unsigned)f2bf(acc[mt+2][nt][1]) << 16);
                pk.z = (unsigned)f2bf(acc[mt][nt][2]) | ((unsigned)f2bf(acc[mt+2][nt][2]) << 16);
                pk.w = (unsigned)f2bf(acc[mt][nt][3]) | ((unsigned)f2bf(acc[mt+2][nt][3]) << 16);
                // c = mt*16 + q*4 + rg, rg contiguous in the uint4
                *(uint4*)(dst + (size_t)pos * 32 + mt * 16 + q * 4) = pk;
            }
        }
    } else {
#pragma unroll
        for (int mt = 0; mt < 4; ++mt) {
#pragma unroll
            for (int nt = 0; nt < 4; ++nt) {
#pragma unroll
                for (int rg = 0; rg < 4; ++rg) {
                    const int co  = mt * 16 + q * 4 + rg;
                    const int pos = dw + nt * 16 + r;
                    ((float*)dstv)[((size_t)(b * 64 + co)) * VOL + pos]
                        = acc[mt][nt][rg] + bias[co];
                }
            }
        }
    }
}

// Trilinear gather, v3: thread = one pos, loops all 32 channels.
//  - offsets: [b][pos][32c] u32 -> 8x dwordx4 per thread (own 128B).
//  - output:  [b][pos][32c] bf16 -> 4x dwordx4 per thread (one full 64B line).
//  - no LDS, no transposes. Lanes d-fastest (ix ~ d is the x-contiguous axis).
__global__ __launch_bounds__(256, 4)
void gather_kernel(const float* __restrict__ x,
                   const unsigned* __restrict__ off32,   // [b][pos][32]
                   unsigned* __restrict__ sampled) {     // [b][pos][32] bf16 (u32 pairs)
    const int t = threadIdx.x;
    const unsigned gid = blockIdx.x;    // 0..2047
    const int b   = gid >> 10;
    const int j   = gid & 1023;
    const int wt4 = j & 3;
    const int dt  = (j >> 2) & 3;
    const int h   = j >> 4;             // 0..63
    const int d_i = t & 15;
    const int w_i = t >> 4;
    const int d = dt * 16 + d_i;
    const int w = wt4 * 16 + w_i;
    const int p = d * 4096 + h * 64 + w;

    const unsigned* op = off32 + ((size_t)(b * VOL + p)) * 32;
    const float* xb_ = x + (size_t)b * 32 * VOL;
    const float fd = (float)d, fh = (float)h, fw = (float)w;

    float outv[32];
#pragma unroll
    for (int cq = 0; cq < 8; ++cq) {
        const uint4 o4 = *(const uint4*)(op + cq * 4);
        const unsigned oarr[4] = {o4.x, o4.y, o4.z, o4.w};
#pragma unroll
        for (int ce = 0; ce < 4; ++ce) {
            const int c = cq * 4 + ce;
            const unsigned ow = oarr[ce];
            const float offw = bf2f((unsigned short)(ow & 0xffffu));
            const float offh = bf2f((unsigned short)(ow >> 16));
            const float* vol = xb_ + (size_t)c * VOL;

            // Faithful-bug mapping: ix=off_h*31.5+d, iy=off_w*31.5+h, iz=off_h*31.5+w
            const float ix = offh * 31.5f + fd;
            const float iy = offw * 31.5f + fh;
            const float iz = offh * 31.5f + fw;

            const float x0f = floorf(ix), y0f = floorf(iy), z0f = floorf(iz);
            const float tx = ix - x0f, ty = iy - y0f, tz = iz - z0f;
            const int ix0 = (int)x0f, iy0 = (int)y0f, iz0 = (int)z0f;

            const int bx0 = iclamp(ix0, 0, 62);
            const bool sel = (ix0 == bx0);
            const float w0x = ((unsigned)ix0 < 64u)       ? (1.f - tx) : 0.f;
            const float w1x = ((unsigned)(ix0 + 1) < 64u) ? tx         : 0.f;

            float out = 0.f;
#pragma unroll
            for (int dz = 0; dz < 2; ++dz) {
                const int zc = iz0 + dz;
                const bool zok = ((unsigned)zc < 64u);
                const int zcc = iclamp(zc, 0, 63);
                const float wz = dz ? tz : 1.f - tz;
#pragma unroll
                for (int dy = 0; dy < 2; ++dy) {
                    const int yc = iy0 + dy;
                    const bool yok = ((unsigned)yc < 64u);
                    const int ycc = iclamp(yc, 0, 63);
                    const float wzy = (zok && yok) ? wz * (dy ? ty : 1.f - ty) : 0.f;

                    const fpair vp = *(const fpair*)&vol[(zcc * 64 + ycc) * 64 + bx0];
                    const float v0 = sel ? vp.x : vp.y;
                    const float v1 = sel ? vp.y : vp.x;
                    out += wzy * (w0x * v0 + w1x * v1);
                }
            }
            outv[c] = out;
        }
    }

    unsigned* sp = sampled + ((size_t)(b * VOL + p)) * 16;
#pragma unroll
    for (int i = 0; i < 4; ++i) {
        uint4 pk;
        pk.x = (unsigned)f2bf(outv[i*8+0]) | ((unsigned)f2bf(outv[i*8+1]) << 16);
        pk.y = (unsigned)f2bf(outv[i*8+2]) | ((unsigned)f2bf(outv[i*8+3]) << 16);
        pk.z = (unsigned)f2bf(outv[i*8+4]) | ((unsigned)f2bf(outv[i*8+5]) << 16);
        pk.w = (unsigned)f2bf(outv[i*8+6]) | ((unsigned)f2bf(outv[i*8+7]) << 16);
        *(uint4*)(sp + i*4) = pk;
    }
}

extern "C" void kernel_launch(void* const* d_in, const int* in_sizes, int n_in,
                              void* d_out, int out_size, void* d_ws, size_t ws_size,
                              hipStream_t stream) {
    (void)in_sizes; (void)n_in; (void)out_size; (void)ws_size;
    const float* x     = (const float*)d_in[0];   // (2,32,64,64,64)
    const float* w_off = (const float*)d_in[1];   // (96,32,3,3,3)
    const float* w_reg = (const float*)d_in[2];   // (64,32,3,3,3)
    const float* b_reg = (const float*)d_in[3];   // (64,)
    float* out = (float*)d_out;                   // (2,64,64,64,64)

    // ws: off32 u32 [2][VOL][32] (64 MiB) | buf (32 MiB: xb, then sampled) | wt1 | wt2
    // buf holds prepacked-x bf16 for conv1, then is REUSED for sampled (xb dead
    // after conv1; stream-ordered).
    unsigned* off32 = (unsigned*)d_ws;
    unsigned* buf   = off32 + (size_t)2 * VOL * 32;
    unsigned short* wt1 = (unsigned short*)(buf + (size_t)2 * VOL * 16);
    unsigned short* wt2 = wt1 + 27 * 64 * 32;

    prep_w_kernel<<<216, 256, 0, stream>>>(w_off, w_reg, wt1, wt2);
    prepack_kernel<<<2048, 256, 0, stream>>>(x, buf);

    dim3 cgrid(32, 32, 2);
    conv_mfma_kernel<true><<<cgrid, 256, 0, stream>>>(
        (const unsigned short*)buf, wt1, nullptr, (void*)off32);

    gather_kernel<<<2048, 256, 0, stream>>>(x, off32, buf);

    conv_mfma_kernel<false><<<cgrid, 256, 0, stream>>>(
        (const unsigned short*)buf, wt2, b_reg, (void*)out);
}

// Round 5
// 444.085 us; speedup vs baseline: 1.0040x; 1.0040x over previous
//
#include <hip/hip_runtime.h>
#include <cstddef>

#define S 64
#define VOL (64*64*64)      // 262144
#define CIN 32

typedef __attribute__((ext_vector_type(8))) short bf16x8;
typedef __attribute__((ext_vector_type(4))) float floatx4;

struct __attribute__((packed, aligned(4))) fpair { float x, y; };

__device__ __forceinline__ unsigned short f2bf(float f) {
    union { float f; unsigned u; } v; v.f = f;
    unsigned r = v.u + 0x7fffu + ((v.u >> 16) & 1u);   // RNE
    return (unsigned short)(r >> 16);
}
__device__ __forceinline__ float bf2f(unsigned short h) {
    union { unsigned u; float f; } v; v.u = ((unsigned)h) << 16;
    return v.f;
}
__device__ __forceinline__ int iclamp(int v, int lo, int hi) {
    return v < lo ? lo : (v > hi ? hi : v);
}

// Async 16B global -> LDS (DMA, no VGPR round-trip). LDS dst is wave-uniform
// base; lane l lands at base + l*16.
__device__ __forceinline__ void gload_lds16(const void* g, void* l) {
    __builtin_amdgcn_global_load_lds(
        (const __attribute__((address_space(1))) void*)g,
        (__attribute__((address_space(3))) void*)l, 16, 0, 0);
}

// Weight prep: src [co][ci][27] fp32 -> dst [tap][co][ci] bf16 (co<64).
__global__ void prep_w_kernel(const float* __restrict__ w_off,
                              const float* __restrict__ w_reg,
                              unsigned short* __restrict__ wt1,
                              unsigned short* __restrict__ wt2) {
    int i = blockIdx.x * 256 + threadIdx.x;   // i = tap*2048 + co*32 + ci
    if (i >= 27 * 64 * 32) return;
    int ci = i & 31;
    int co = (i >> 5) & 63;
    int tap = i >> 11;
    wt1[i] = f2bf(w_off[(co * 32 + ci) * 27 + tap]);
    wt2[i] = f2bf(w_reg[(co * 32 + ci) * 27 + tap]);
}

// x fp32 [b][c][pos] -> xb bf16 [b][pos][32ci], v2: output bounced through LDS
// so every global store instruction is 1KB lane-contiguous (full 64B lines).
__global__ __launch_bounds__(256)
void prepack_kernel(const float* __restrict__ x, uint4* __restrict__ xb4) {
    __shared__ uint4 pbuf[1024];   // 16 KB
    const int t = threadIdx.x;
    const unsigned id0 = blockIdx.x * 256;
    const unsigned id  = id0 + t;                 // b*VOL + pos (pos contiguous)
    const int b   = id >> 18;                     // VOL = 2^18
    const int pos = id & (VOL - 1);
    const float* sp = x + (size_t)b * 32 * VOL + pos;
    float v[32];
#pragma unroll
    for (int c = 0; c < 32; ++c) v[c] = sp[(size_t)c * VOL];
#pragma unroll
    for (int i = 0; i < 4; ++i) {
        uint4 pk;
        pk.x = (unsigned)f2bf(v[i*8+0]) | ((unsigned)f2bf(v[i*8+1]) << 16);
        pk.y = (unsigned)f2bf(v[i*8+2]) | ((unsigned)f2bf(v[i*8+3]) << 16);
        pk.z = (unsigned)f2bf(v[i*8+4]) | ((unsigned)f2bf(v[i*8+5]) << 16);
        pk.w = (unsigned)f2bf(v[i*8+6]) | ((unsigned)f2bf(v[i*8+7]) << 16);
        pbuf[t * 4 + (i ^ (t & 3))] = pk;         // XOR-swizzled chunk
    }
    __syncthreads();
#pragma unroll
    for (int i = 0; i < 4; ++i) {
        const int g  = i * 256 + t;
        const int ch = g & 3;
        const int lw = g >> 2;
        xb4[(size_t)id0 * 4 + g] = pbuf[lw * 4 + (ch ^ (lw & 3))];
    }
}

// Implicit-GEMM 3x3x3 conv via MFMA 16x16x32 bf16.  v3 (unchanged; verified).
//
// Input layout: bf16 [b][pos][32ci] (channels fastest) -> one LDS row (z,y) is a
// CONTIGUOUS 4KB global row => staging is pure global_load_lds_dwordx4 (async DMA).
// XOR chunk swizzle (logical 16B chunk jj of slot s stored at physical jj^((s>>1)&3))
// is applied by pre-swizzling the per-lane GLOBAL source address; LDS dest linear.
//
// Block: 256 thr = 4 waves. Output tile: 64co x 256pos = (d0..+1) x (h0..+1) x w0..63.
// Wave wv: dd=wv>>1, hh=wv&1. LDS [row 0..15][slot w 0..63][ci 0..31] bf16 = 64KB.
// A-frag: lane holds W[co=base+(lane&15)][ci=(lane>>4)*8+j].
// B-frag: lane holds X[ci=(lane>>4)*8+j][pos=base+(lane&15)].
// C/D: col(=pos)=lane&15, row(=co)=(lane>>4)*4+reg  [measured m89/m91].
//
// WRITE_OFF epilogue: offsets packed u32 in [b][pos][32c] (lo=offw(c), hi=offh(c+32)),
// stored as uint4 (4 c per lane, contiguous).
template <bool WRITE_OFF>
__global__ __launch_bounds__(256, 2)
void conv_mfma_kernel(const unsigned short* __restrict__ src,  // [b][pos][32] bf16
                      const unsigned short* __restrict__ wt,   // [27][64][32] bf16
                      const float* __restrict__ bias,          // used when !WRITE_OFF
                      void* __restrict__ dstv) {
    __shared__ unsigned short lds[16 * 64 * 32];   // 65536 B

    const int d0 = blockIdx.x * 2;
    const int h0 = blockIdx.y * 2;
    const int b  = blockIdx.z;
    const int t  = threadIdx.x;
    const int lane = t & 63;
    const int wv   = t >> 6;

    // ---- async staging: 4 rows per wave, 4 x 1KB issues per row ----
    const int sl = lane >> 2;                      // slot sub-index 0..15
    const int js = (lane & 3) ^ ((lane >> 3) & 3); // inverse-swizzled source chunk
    const char* sbase = (const char*)src + (size_t)b * VOL * 64;
#pragma unroll
    for (int rr2 = 0; rr2 < 4; ++rr2) {
        const int rowi = (wv << 2) + rr2;
        const int z = d0 - 1 + (rowi >> 2);
        const int y = h0 - 1 + (rowi & 3);
        char* ldsrow = (char*)lds + (rowi << 12);
        if (((unsigned)z < 64u) && ((unsigned)y < 64u)) {
            const char* gb = sbase + ((size_t)(z * 4096 + y * 64)) * 64
                           + (sl << 6) + (js << 4);
#pragma unroll
            for (int k = 0; k < 4; ++k)
                gload_lds16(gb + (k << 10), ldsrow + (k << 10));
        } else {
            const uint4 z4 = make_uint4(0, 0, 0, 0);
#pragma unroll
            for (int k = 0; k < 4; ++k)
                *(uint4*)(ldsrow + (k << 10) + (lane << 4)) = z4;
        }
    }
    __syncthreads();   // drains vmcnt (global_load_lds) + lgkmcnt (zero writes)

    // ---- compute ----
    const int r    = lane & 15;
    const int q    = lane >> 4;
    const int dd   = wv >> 1;     // output d = d0 + dd
    const int hh   = wv & 1;      // output h = h0 + hh

    int P[4][3];
#pragma unroll
    for (int nt = 0; nt < 4; ++nt)
#pragma unroll
        for (int kw = 0; kw < 3; ++kw) {
            const int s  = nt * 16 + r + kw - 1;
            const int sc = s & 63;
            P[nt][kw] = (sc << 6) + ((q ^ ((sc >> 1) & 3)) << 4);
        }

    floatx4 acc[4][4];
#pragma unroll
    for (int mt = 0; mt < 4; ++mt)
#pragma unroll
        for (int nt = 0; nt < 4; ++nt)
#pragma unroll
            for (int rg = 0; rg < 4; ++rg) acc[mt][nt][rg] = 0.f;

    const bf16x8 z8 = {0, 0, 0, 0, 0, 0, 0, 0};

#pragma unroll
    for (int tap = 0; tap < 27; ++tap) {
        const int kd = tap / 9;
        const int kh = (tap % 9) / 3;
        const int kw = tap % 3;
        const int rowb = ((((dd + kd) << 2) + hh + kh) << 12);   // row * 4096 B

        bf16x8 afr[4];
#pragma unroll
        for (int mt = 0; mt < 4; ++mt)
            afr[mt] = *(const bf16x8*)&wt[tap * 2048 + (mt * 16 + r) * 32 + q * 8];

        bf16x8 bfr[4];
#pragma unroll
        for (int nt = 0; nt < 4; ++nt)
            bfr[nt] = *(const bf16x8*)((const char*)lds + rowb + P[nt][kw]);

        if (kw == 0) { if (r == 0)  bfr[0] = z8; }
        if (kw == 2) { if (r == 15) bfr[3] = z8; }

#pragma unroll
        for (int mt = 0; mt < 4; ++mt)
#pragma unroll
            for (int nt = 0; nt < 4; ++nt)
                acc[mt][nt] = __builtin_amdgcn_mfma_f32_16x16x32_bf16(
                                  afr[mt], bfr[nt], acc[mt][nt], 0, 0, 0);
    }

    // ---- epilogue ----
    const int dw = (d0 + dd) * 4096 + (h0 + hh) * 64;
    if (WRITE_OFF) {
        unsigned* dst = (unsigned*)dstv + (size_t)b * VOL * 32;
#pragma unroll
        for (int mt = 0; mt < 2; ++mt) {
#pragma unroll
            for (int nt = 0; nt < 4; ++nt) {
                const int pos = dw + nt * 16 + r;
                uint4 pk;
                pk.x = (unsigned)f2bf(acc[mt][nt][0]) | ((unsigned)f2bf(acc[mt+2][nt][0]) << 16);
                pk.y = (unsigned)f2bf(acc[mt][nt][1]) | ((unsigned)f2bf(acc[mt+2][nt][1]) << 16);
                pk.z = (unsigned)f2bf(acc[mt][nt][2]) | ((unsigned)f2bf(acc[mt+2][nt][2]) << 16);
                pk.w = (unsigned)f2bf(acc[mt][nt][3]) | ((unsigned)f2bf(acc[mt+2][nt][3]) << 16);
                // c = mt*16 + q*4 + rg, rg contiguous in the uint4
                *(uint4*)(dst + (size_t)pos * 32 + mt * 16 + q * 4) = pk;
            }
        }
    } else {
#pragma unroll
        for (int mt = 0; mt < 4; ++mt) {
#pragma unroll
            for (int nt = 0; nt < 4; ++nt) {
#pragma unroll
                for (int rg = 0; rg < 4; ++rg) {
                    const int co  = mt * 16 + q * 4 + rg;
                    const int pos = dw + nt * 16 + r;
                    ((float*)dstv)[((size_t)(b * 64 + co)) * VOL + pos]
                        = acc[mt][nt][rg] + bias[co];
                }
            }
        }
    }
}

// Trilinear gather, v4: thread = one pos, loops all 32 channels.
//  - offsets staged through XOR-swizzled LDS: global reads are 1KB/wave
//    contiguous dwordx4; per-thread 128B row read conflict-free from LDS.
//  - output bounced through LDS: global stores are 1KB/wave contiguous
//    (full 64B lines per instruction; kills the 4.2x WRITE_SIZE inflation).
//  - x tap reads unchanged: lanes d-fastest (ix ~ d is the contiguous axis).
__global__ __launch_bounds__(256, 4)
void gather_kernel(const float* __restrict__ x,
                   const uint4* __restrict__ off4,    // [b][pos][8] = 32 u32/pos
                   uint4* __restrict__ samp4) {       // [b][pos][4] = 64B bf16/pos
    __shared__ uint4 lbuf[2048];   // 32 KB; offsets stage, then out-bounce (front 16KB)

    const int t = threadIdx.x;
    const unsigned gid = blockIdx.x;    // 0..2047
    const int b   = gid >> 10;
    const int j   = gid & 1023;
    const int wt4 = j & 3;
    const int dt  = (j >> 2) & 3;
    const int h   = j >> 4;             // 0..63

    const size_t vbase = (size_t)b * VOL;
    const int pcorner = dt * 16 * 4096 + h * 64 + wt4 * 16;  // pos at (seg=0,wl=0)

    // ---- stage offsets: 32 KB in 8 rounds of 1KB/wave contiguous loads ----
    const uint4* ob = off4 + (vbase + pcorner) * 8;
#pragma unroll
    for (int i = 0; i < 8; ++i) {
        const int f   = i * 256 + t;
        const int seg = f >> 7;          // d-index 0..15 (256KB-strided segments)
        const int o   = f & 127;         // wl*8 + ch, contiguous 2KB within seg
        const int wl  = o >> 3;
        const int ch  = o & 7;
        const uint4 v = ob[(size_t)seg * 32768 + o];
        const int lid = seg * 16 + wl;
        lbuf[lid * 8 + (ch ^ (seg & 7))] = v;     // swizzle keyed on lid>>4 (=seg)
    }
    __syncthreads();

    const int d_i = t & 15;
    const int w_i = t >> 4;
    const int d = dt * 16 + d_i;
    const int w = wt4 * 16 + w_i;
    const int lid = d_i * 16 + w_i;

    const float* xb_ = x + vbase * 32;
    const float fd = (float)d, fh = (float)h, fw = (float)w;

    float outv[32];
#pragma unroll
    for (int cq = 0; cq < 8; ++cq) {
        const uint4 o4 = lbuf[lid * 8 + (cq ^ (d_i & 7))];
        const unsigned oarr[4] = {o4.x, o4.y, o4.z, o4.w};
#pragma unroll
        for (int ce = 0; ce < 4; ++ce) {
            const int c = cq * 4 + ce;
            const unsigned ow = oarr[ce];
            const float offw = bf2f((unsigned short)(ow & 0xffffu));
            const float offh = bf2f((unsigned short)(ow >> 16));
            const float* vol = xb_ + (size_t)c * VOL;

            // Faithful-bug mapping: ix=off_h*31.5+d, iy=off_w*31.5+h, iz=off_h*31.5+w
            const float ix = offh * 31.5f + fd;
            const float iy = offw * 31.5f + fh;
            const float iz = offh * 31.5f + fw;

            const float x0f = floorf(ix), y0f = floorf(iy), z0f = floorf(iz);
            const float tx = ix - x0f, ty = iy - y0f, tz = iz - z0f;
            const int ix0 = (int)x0f, iy0 = (int)y0f, iz0 = (int)z0f;

            const int bx0 = iclamp(ix0, 0, 62);
            const bool sel = (ix0 == bx0);
            const float w0x = ((unsigned)ix0 < 64u)       ? (1.f - tx) : 0.f;
            const float w1x = ((unsigned)(ix0 + 1) < 64u) ? tx         : 0.f;

            float out = 0.f;
#pragma unroll
            for (int dz = 0; dz < 2; ++dz) {
                const int zc = iz0 + dz;
                const bool zok = ((unsigned)zc < 64u);
                const int zcc = iclamp(zc, 0, 63);
                const float wz = dz ? tz : 1.f - tz;
#pragma unroll
                for (int dy = 0; dy < 2; ++dy) {
                    const int yc = iy0 + dy;
                    const bool yok = ((unsigned)yc < 64u);
                    const int ycc = iclamp(yc, 0, 63);
                    const float wzy = (zok && yok) ? wz * (dy ? ty : 1.f - ty) : 0.f;

                    const fpair vp = *(const fpair*)&vol[(zcc * 64 + ycc) * 64 + bx0];
                    const float v0 = sel ? vp.x : vp.y;
                    const float v1 = sel ? vp.y : vp.x;
                    out += wzy * (w0x * v0 + w1x * v1);
                }
            }
            outv[c] = out;
        }
    }

    __syncthreads();   // all offset reads from lbuf complete before reuse

    // ---- out bounce: swizzled LDS, then 4 rounds of 1KB/wave contiguous stores ----
#pragma unroll
    for (int i = 0; i < 4; ++i) {
        uint4 pk;
        pk.x = (unsigned)f2bf(outv[i*8+0]) | ((unsigned)f2bf(outv[i*8+1]) << 16);
        pk.y = (unsigned)f2bf(outv[i*8+2]) | ((unsigned)f2bf(outv[i*8+3]) << 16);
        pk.z = (unsigned)f2bf(outv[i*8+4]) | ((unsigned)f2bf(outv[i*8+5]) << 16);
        pk.w = (unsigned)f2bf(outv[i*8+6]) | ((unsigned)f2bf(outv[i*8+7]) << 16);
        lbuf[lid * 4 + (i ^ (d_i & 3))] = pk;     // swizzle keyed on lid>>4 (=d_i)
    }
    __syncthreads();

    uint4* sb = samp4 + (vbase + pcorner) * 4;
#pragma unroll
    for (int i = 0; i < 4; ++i) {
        const int g   = i * 256 + t;
        const int ch  = g & 3;
        const int lw  = g >> 2;
        const int seg = lw >> 4;
        const int o   = g & 63;          // wl*4 + ch, contiguous 1KB within seg
        sb[(size_t)seg * 16384 + o] = lbuf[lw * 4 + (ch ^ (seg & 3))];
    }
}

extern "C" void kernel_launch(void* const* d_in, const int* in_sizes, int n_in,
                              void* d_out, int out_size, void* d_ws, size_t ws_size,
                              hipStream_t stream) {
    (void)in_sizes; (void)n_in; (void)out_size; (void)ws_size;
    const float* x     = (const float*)d_in[0];   // (2,32,64,64,64)
    const float* w_off = (const float*)d_in[1];   // (96,32,3,3,3)
    const float* w_reg = (const float*)d_in[2];   // (64,32,3,3,3)
    const float* b_reg = (const float*)d_in[3];   // (64,)
    float* out = (float*)d_out;                   // (2,64,64,64,64)

    // ws: off32 u32 [2][VOL][32] (64 MiB) | buf (32 MiB: xb, then sampled) | wt1 | wt2
    // buf holds prepacked-x bf16 for conv1, then is REUSED for sampled (xb dead
    // after conv1; stream-ordered).
    unsigned* off32 = (unsigned*)d_ws;
    unsigned* buf   = off32 + (size_t)2 * VOL * 32;
    unsigned short* wt1 = (unsigned short*)(buf + (size_t)2 * VOL * 16);
    unsigned short* wt2 = wt1 + 27 * 64 * 32;

    prep_w_kernel<<<216, 256, 0, stream>>>(w_off, w_reg, wt1, wt2);
    prepack_kernel<<<2048, 256, 0, stream>>>(x, (uint4*)buf);

    dim3 cgrid(32, 32, 2);
    conv_mfma_kernel<true><<<cgrid, 256, 0, stream>>>(
        (const unsigned short*)buf, wt1, nullptr, (void*)off32);

    gather_kernel<<<2048, 256, 0, stream>>>(x, (const uint4*)off32, (uint4*)buf);

    conv_mfma_kernel<false><<<cgrid, 256, 0, stream>>>(
        (const unsigned short*)buf, wt2, b_reg, (void*)out);
}

// Round 6
// 441.806 us; speedup vs baseline: 1.0091x; 1.0052x over previous
//
#include <hip/hip_runtime.h>
#include <cstddef>

#define S 64
#define VOL (64*64*64)      // 262144
#define CIN 32

typedef __attribute__((ext_vector_type(8))) short bf16x8;
typedef __attribute__((ext_vector_type(4))) float floatx4;

struct __attribute__((packed, aligned(4))) fpair { float x, y; };

__device__ __forceinline__ unsigned short f2bf(float f) {
    union { float f; unsigned u; } v; v.f = f;
    unsigned r = v.u + 0x7fffu + ((v.u >> 16) & 1u);   // RNE
    return (unsigned short)(r >> 16);
}
__device__ __forceinline__ float bf2f(unsigned short h) {
    union { unsigned u; float f; } v; v.u = ((unsigned)h) << 16;
    return v.f;
}
__device__ __forceinline__ int iclamp(int v, int lo, int hi) {
    return v < lo ? lo : (v > hi ? hi : v);
}

// Async 16B global -> LDS (DMA, no VGPR round-trip). LDS dst is wave-uniform
// base; lane l lands at base + l*16.
__device__ __forceinline__ void gload_lds16(const void* g, void* l) {
    __builtin_amdgcn_global_load_lds(
        (const __attribute__((address_space(1))) void*)g,
        (__attribute__((address_space(3))) void*)l, 16, 0, 0);
}

// Weight prep: src [co][ci][27] fp32 -> dst [tap][co][ci] bf16 (co<64).
__global__ void prep_w_kernel(const float* __restrict__ w_off,
                              const float* __restrict__ w_reg,
                              unsigned short* __restrict__ wt1,
                              unsigned short* __restrict__ wt2) {
    int i = blockIdx.x * 256 + threadIdx.x;   // i = tap*2048 + co*32 + ci
    if (i >= 27 * 64 * 32) return;
    int ci = i & 31;
    int co = (i >> 5) & 63;
    int tap = i >> 11;
    wt1[i] = f2bf(w_off[(co * 32 + ci) * 27 + tap]);
    wt2[i] = f2bf(w_reg[(co * 32 + ci) * 27 + tap]);
}

// x fp32 [b][c][pos] -> xb bf16 [b][pos][32ci] (packed u32 pairs), LDS-bounced
// stores (1KB lane-contiguous).
__global__ __launch_bounds__(256)
void prepack_kernel(const float* __restrict__ x, uint4* __restrict__ xb4) {
    __shared__ uint4 pbuf[1024];   // 16 KB
    const int t = threadIdx.x;
    const unsigned id0 = blockIdx.x * 256;
    const unsigned id  = id0 + t;                 // b*VOL + pos (pos contiguous)
    const int b   = id >> 18;                     // VOL = 2^18
    const int pos = id & (VOL - 1);
    const float* sp = x + (size_t)b * 32 * VOL + pos;
    float v[32];
#pragma unroll
    for (int c = 0; c < 32; ++c) v[c] = sp[(size_t)c * VOL];
#pragma unroll
    for (int i = 0; i < 4; ++i) {
        uint4 pk;
        pk.x = (unsigned)f2bf(v[i*8+0]) | ((unsigned)f2bf(v[i*8+1]) << 16);
        pk.y = (unsigned)f2bf(v[i*8+2]) | ((unsigned)f2bf(v[i*8+3]) << 16);
        pk.z = (unsigned)f2bf(v[i*8+4]) | ((unsigned)f2bf(v[i*8+5]) << 16);
        pk.w = (unsigned)f2bf(v[i*8+6]) | ((unsigned)f2bf(v[i*8+7]) << 16);
        pbuf[t * 4 + (i ^ (t & 3))] = pk;         // XOR-swizzled chunk
    }
    __syncthreads();
#pragma unroll
    for (int i = 0; i < 4; ++i) {
        const int g  = i * 256 + t;
        const int ch = g & 3;
        const int lw = g >> 2;
        xb4[(size_t)id0 * 4 + g] = pbuf[lw * 4 + (ch ^ (lw & 3))];
    }
}

// Implicit-GEMM 3x3x3 conv via MFMA 16x16x32 bf16.  v4.
//
// Same dataflow as v3 (verified), plus a 2-phase pipeline: wave wv stages
// exactly z-plane wv (rows wv*4..wv*4+3); plane 3 is only consumed by the
// kd=2 taps, so barrier A drains only waves 0-2 (wave 3's 16KB stays in
// flight under the first 18 taps), barrier B drains wave 3 before kd=2.
template <bool WRITE_OFF>
__global__ __launch_bounds__(256, 2)
void conv_mfma_kernel(const unsigned short* __restrict__ src,  // [b][pos][32] bf16
                      const unsigned short* __restrict__ wt,   // [27][64][32] bf16
                      const float* __restrict__ bias,          // used when !WRITE_OFF
                      void* __restrict__ dstv) {
    __shared__ unsigned short lds[16 * 64 * 32];   // 65536 B

    const int d0 = blockIdx.x * 2;
    const int h0 = blockIdx.y * 2;
    const int b  = blockIdx.z;
    const int t  = threadIdx.x;
    const int lane = t & 63;
    const int wv   = t >> 6;

    // ---- async staging: wave wv loads plane wv (4 rows), 4 x 1KB per row ----
    const int sl = lane >> 2;                      // slot sub-index 0..15
    const int js = (lane & 3) ^ ((lane >> 3) & 3); // inverse-swizzled source chunk
    const char* sbase = (const char*)src + (size_t)b * VOL * 64;
#pragma unroll
    for (int rr2 = 0; rr2 < 4; ++rr2) {
        const int rowi = (wv << 2) + rr2;          // zz = wv, yy = rr2
        const int z = d0 - 1 + (rowi >> 2);
        const int y = h0 - 1 + (rowi & 3);
        char* ldsrow = (char*)lds + (rowi << 12);
        if (((unsigned)z < 64u) && ((unsigned)y < 64u)) {
            const char* gb = sbase + ((size_t)(z * 4096 + y * 64)) * 64
                           + (sl << 6) + (js << 4);
#pragma unroll
            for (int k = 0; k < 4; ++k)
                gload_lds16(gb + (k << 10), ldsrow + (k << 10));
        } else {
            const uint4 z4 = make_uint4(0, 0, 0, 0);
#pragma unroll
            for (int k = 0; k < 4; ++k)
                *(uint4*)(ldsrow + (k << 10) + (lane << 4)) = z4;
        }
    }

    // ---- per-lane constants + acc init (VALU, overlaps the drain) ----
    const int r    = lane & 15;
    const int q    = lane >> 4;
    const int dd   = wv >> 1;     // output d = d0 + dd
    const int hh   = wv & 1;      // output h = h0 + hh

    int P[4][3];
#pragma unroll
    for (int nt = 0; nt < 4; ++nt)
#pragma unroll
        for (int kw = 0; kw < 3; ++kw) {
            const int s  = nt * 16 + r + kw - 1;
            const int sc = s & 63;
            P[nt][kw] = (sc << 6) + ((q ^ ((sc >> 1) & 3)) << 4);
        }

    floatx4 acc[4][4];
#pragma unroll
    for (int mt = 0; mt < 4; ++mt)
#pragma unroll
        for (int nt = 0; nt < 4; ++nt)
#pragma unroll
            for (int rg = 0; rg < 4; ++rg) acc[mt][nt][rg] = 0.f;

    // ---- barrier A: planes 0-2 visible; wave 3's plane-3 loads in flight ----
    asm volatile("s_waitcnt lgkmcnt(0)" ::: "memory");
    if (wv < 3) asm volatile("s_waitcnt vmcnt(0)" ::: "memory");
    __builtin_amdgcn_s_barrier();
    __builtin_amdgcn_sched_barrier(0);

    const bf16x8 z8 = {0, 0, 0, 0, 0, 0, 0, 0};

#pragma unroll
    for (int tap = 0; tap < 27; ++tap) {
        if (tap == 18) {
            // ---- barrier B: plane 3 now needed (kd=2 taps) ----
            if (wv == 3) asm volatile("s_waitcnt vmcnt(0)" ::: "memory");
            __builtin_amdgcn_s_barrier();
            __builtin_amdgcn_sched_barrier(0);
        }
        const int kd = tap / 9;
        const int kh = (tap % 9) / 3;
        const int kw = tap % 3;
        const int rowb = ((((dd + kd) << 2) + hh + kh) << 12);   // row * 4096 B

        bf16x8 afr[4];
#pragma unroll
        for (int mt = 0; mt < 4; ++mt)
            afr[mt] = *(const bf16x8*)&wt[tap * 2048 + (mt * 16 + r) * 32 + q * 8];

        bf16x8 bfr[4];
#pragma unroll
        for (int nt = 0; nt < 4; ++nt)
            bfr[nt] = *(const bf16x8*)((const char*)lds + rowb + P[nt][kw]);

        if (kw == 0) { if (r == 0)  bfr[0] = z8; }
        if (kw == 2) { if (r == 15) bfr[3] = z8; }

#pragma unroll
        for (int mt = 0; mt < 4; ++mt)
#pragma unroll
            for (int nt = 0; nt < 4; ++nt)
                acc[mt][nt] = __builtin_amdgcn_mfma_f32_16x16x32_bf16(
                                  afr[mt], bfr[nt], acc[mt][nt], 0, 0, 0);
    }

    // ---- epilogue ----
    const int dw = (d0 + dd) * 4096 + (h0 + hh) * 64;
    if (WRITE_OFF) {
        unsigned* dst = (unsigned*)dstv + (size_t)b * VOL * 32;
#pragma unroll
        for (int mt = 0; mt < 2; ++mt) {
#pragma unroll
            for (int nt = 0; nt < 4; ++nt) {
                const int pos = dw + nt * 16 + r;
                uint4 pk;
                pk.x = (unsigned)f2bf(acc[mt][nt][0]) | ((unsigned)f2bf(acc[mt+2][nt][0]) << 16);
                pk.y = (unsigned)f2bf(acc[mt][nt][1]) | ((unsigned)f2bf(acc[mt+2][nt][1]) << 16);
                pk.z = (unsigned)f2bf(acc[mt][nt][2]) | ((unsigned)f2bf(acc[mt+2][nt][2]) << 16);
                pk.w = (unsigned)f2bf(acc[mt][nt][3]) | ((unsigned)f2bf(acc[mt+2][nt][3]) << 16);
                // c = mt*16 + q*4 + rg, rg contiguous in the uint4
                *(uint4*)(dst + (size_t)pos * 32 + mt * 16 + q * 4) = pk;
            }
        }
    } else {
#pragma unroll
        for (int mt = 0; mt < 4; ++mt) {
#pragma unroll
            for (int nt = 0; nt < 4; ++nt) {
#pragma unroll
                for (int rg = 0; rg < 4; ++rg) {
                    const int co  = mt * 16 + q * 4 + rg;
                    const int pos = dw + nt * 16 + r;
                    ((float*)dstv)[((size_t)(b * 64 + co)) * VOL + pos]
                        = acc[mt][nt][rg] + bias[co];
                }
            }
        }
    }
}

// Trilinear gather, v5: thread = one pos; channels processed in 4 groups of 8
// to keep VGPRs <= 64 so __launch_bounds__(256,8) gives 8 blocks/CU (2x the
// v3/v4 occupancy; the kernel is latency-bound). No LDS, no barriers (v4's
// bounce was a measured regression). Lanes d-fastest: ix ~ d is x-contiguous,
// so the 8B tap loads coalesce; offset/output lines are consumed whole per
// thread, so scattering them costs requests, not HBM bytes.
__global__ __launch_bounds__(256, 8)
void gather_kernel(const float* __restrict__ x,
                   const uint4* __restrict__ off4,    // [b][pos][8] = 32 u32/pos
                   uint4* __restrict__ samp4) {       // [b][pos][4] = 64B bf16/pos
    const int t = threadIdx.x;
    const unsigned gid = blockIdx.x;    // 0..2047
    const int b   = gid >> 10;
    const int j   = gid & 1023;
    const int wt4 = j & 3;
    const int dt  = (j >> 2) & 3;
    const int h   = j >> 4;             // 0..63
    const int d_i = t & 15;
    const int w_i = t >> 4;
    const int d = dt * 16 + d_i;
    const int w = wt4 * 16 + w_i;
    const int p = d * 4096 + h * 64 + w;

    const uint4* op = off4 + ((size_t)b * VOL + p) * 8;
    uint4* sp       = samp4 + ((size_t)b * VOL + p) * 4;
    const float* xb_ = x + (size_t)b * 32 * VOL;
    const float fd = (float)d, fh = (float)h, fw = (float)w;

#pragma unroll 1
    for (int g = 0; g < 4; ++g) {
        const uint4 oA = op[g * 2 + 0];
        const uint4 oB = op[g * 2 + 1];
        const unsigned oarr[8] = {oA.x, oA.y, oA.z, oA.w, oB.x, oB.y, oB.z, oB.w};
        float outv[8];
#pragma unroll
        for (int ce = 0; ce < 8; ++ce) {
            const int c = g * 8 + ce;
            const unsigned ow = oarr[ce];
            const float offw = bf2f((unsigned short)(ow & 0xffffu));
            const float offh = bf2f((unsigned short)(ow >> 16));
            const float* vol = xb_ + (size_t)c * VOL;

            // Faithful-bug mapping: ix=off_h*31.5+d, iy=off_w*31.5+h, iz=off_h*31.5+w
            const float ix = offh * 31.5f + fd;
            const float iy = offw * 31.5f + fh;
            const float iz = offh * 31.5f + fw;

            const float x0f = floorf(ix), y0f = floorf(iy), z0f = floorf(iz);
            const float tx = ix - x0f, ty = iy - y0f, tz = iz - z0f;
            const int ix0 = (int)x0f, iy0 = (int)y0f, iz0 = (int)z0f;

            const int bx0 = iclamp(ix0, 0, 62);
            const bool sel = (ix0 == bx0);
            const float w0x = ((unsigned)ix0 < 64u)       ? (1.f - tx) : 0.f;
            const float w1x = ((unsigned)(ix0 + 1) < 64u) ? tx         : 0.f;

            float out = 0.f;
#pragma unroll
            for (int dz = 0; dz < 2; ++dz) {
                const int zc = iz0 + dz;
                const bool zok = ((unsigned)zc < 64u);
                const int zcc = iclamp(zc, 0, 63);
                const float wz = dz ? tz : 1.f - tz;
#pragma unroll
                for (int dy = 0; dy < 2; ++dy) {
                    const int yc = iy0 + dy;
                    const bool yok = ((unsigned)yc < 64u);
                    const int ycc = iclamp(yc, 0, 63);
                    const float wzy = (zok && yok) ? wz * (dy ? ty : 1.f - ty) : 0.f;

                    const fpair vp = *(const fpair*)&vol[(zcc * 64 + ycc) * 64 + bx0];
                    const float v0 = sel ? vp.x : vp.y;
                    const float v1 = sel ? vp.y : vp.x;
                    out += wzy * (w0x * v0 + w1x * v1);
                }
            }
            outv[ce] = out;
        }
        uint4 pk;
        pk.x = (unsigned)f2bf(outv[0]) | ((unsigned)f2bf(outv[1]) << 16);
        pk.y = (unsigned)f2bf(outv[2]) | ((unsigned)f2bf(outv[3]) << 16);
        pk.z = (unsigned)f2bf(outv[4]) | ((unsigned)f2bf(outv[5]) << 16);
        pk.w = (unsigned)f2bf(outv[6]) | ((unsigned)f2bf(outv[7]) << 16);
        sp[g] = pk;
    }
}

extern "C" void kernel_launch(void* const* d_in, const int* in_sizes, int n_in,
                              void* d_out, int out_size, void* d_ws, size_t ws_size,
                              hipStream_t stream) {
    (void)in_sizes; (void)n_in; (void)out_size; (void)ws_size;
    const float* x     = (const float*)d_in[0];   // (2,32,64,64,64)
    const float* w_off = (const float*)d_in[1];   // (96,32,3,3,3)
    const float* w_reg = (const float*)d_in[2];   // (64,32,3,3,3)
    const float* b_reg = (const float*)d_in[3];   // (64,)
    float* out = (float*)d_out;                   // (2,64,64,64,64)

    // ws: off32 u32 [2][VOL][32] (64 MiB) | buf (32 MiB: xb, then sampled) | wt1 | wt2
    // buf holds prepacked-x bf16 for conv1, then is REUSED for sampled (xb dead
    // after conv1; stream-ordered).
    unsigned* off32 = (unsigned*)d_ws;
    unsigned* buf   = off32 + (size_t)2 * VOL * 32;
    unsigned short* wt1 = (unsigned short*)(buf + (size_t)2 * VOL * 16);
    unsigned short* wt2 = wt1 + 27 * 64 * 32;

    prep_w_kernel<<<216, 256, 0, stream>>>(w_off, w_reg, wt1, wt2);
    prepack_kernel<<<2048, 256, 0, stream>>>(x, (uint4*)buf);

    dim3 cgrid(32, 32, 2);
    conv_mfma_kernel<true><<<cgrid, 256, 0, stream>>>(
        (const unsigned short*)buf, wt1, nullptr, (void*)off32);

    gather_kernel<<<2048, 256, 0, stream>>>(x, (const uint4*)off32, (uint4*)buf);

    conv_mfma_kernel<false><<<cgrid, 256, 0, stream>>>(
        (const unsigned short*)buf, wt2, b_reg, (void*)out);
}